// Round 10
// baseline (1462.442 us; speedup 1.0000x reference)
//
#include <hip/hip_runtime.h>
#include <cstdint>
#include <cstddef>

// Problem constants: B=16, T=4096, D_IN=H=512, L=2, 3H=1536
#define BB 16
#define TT 4096
#define DD 512
#define NG 1536
#define NCH 128           // chunks per chain
#define CS  (TT / NCH)    // 32 timesteps per chunk
#define NCHAIN (BB * DD)  // 8192 chains

typedef __bf16 bf16x8 __attribute__((ext_vector_type(8)));
typedef float f32x4 __attribute__((ext_vector_type(4)));
typedef unsigned short u16;
typedef __attribute__((ext_vector_type(2))) unsigned short u16x2;

__device__ __forceinline__ u16 f2bf(float f) {
  union { float f; unsigned u; } v; v.f = f;
  return (u16)((v.u + 0x7FFFu + ((v.u >> 16) & 1u)) >> 16);
}
__device__ __forceinline__ float bf2f(u16 s) {
  union { unsigned u; float f; } v; v.u = ((unsigned)s) << 16;
  return v.f;
}
__device__ __forceinline__ float sigm(float x) {
  return 1.f / (1.f + __expf(-x));
}

// async global->LDS, 16B per lane. LDS dest = wave-uniform base + lane*16.
__device__ __forceinline__ void gload_lds16(const void* g, void* l) {
  __builtin_amdgcn_global_load_lds(
      (const __attribute__((address_space(1))) unsigned*)g,
      (__attribute__((address_space(3))) unsigned*)l, 16, 0, 0);
}

#define BAR() __builtin_amdgcn_s_barrier()

// ---------------------------------------------------------------------------
// fp32 -> bf16 bulk convert (x: 201 MB traffic; W0/W1: tiny)
// ---------------------------------------------------------------------------
__global__ __launch_bounds__(256) void f32_to_bf16(
    const float* __restrict__ in, u16* __restrict__ out, long n)
{
  const long stride = (long)gridDim.x * 256 * 8;
  for (long i = ((long)blockIdx.x * 256 + threadIdx.x) * 8; i < n; i += stride) {
    float4 a = *reinterpret_cast<const float4*>(in + i);
    float4 b = *reinterpret_cast<const float4*>(in + i + 4);
    uint4 p;
    p.x = (unsigned)f2bf(a.x) | ((unsigned)f2bf(a.y) << 16);
    p.y = (unsigned)f2bf(a.z) | ((unsigned)f2bf(a.w) << 16);
    p.z = (unsigned)f2bf(b.x) | ((unsigned)f2bf(b.y) << 16);
    p.w = (unsigned)f2bf(b.z) | ((unsigned)f2bf(b.w) << 16);
    *reinterpret_cast<uint4*>(out + i) = p;
  }
}

// ---------------------------------------------------------------------------
// GEMM (unchanged from R9 — validated): 128x256 tile, BK=32, 8 waves of
// 64x64, triple-buffered depth-2 prefetch, counted vmcnt(6), LDS-bounce
// epilogue. ~130 us/dispatch (plateau across 3 schedule variants).
// ---------------------------------------------------------------------------
__global__ __launch_bounds__(512, 4) void gemmB(
    const u16* __restrict__ A, const u16* __restrict__ W,
    const float* __restrict__ bias, u16* __restrict__ out)
{
  __shared__ __align__(16) u16 SMEM[36864];   // 72 KB
  u16* const Ab[3] = {SMEM, SMEM + 4096, SMEM + 8192};           // 128x32
  u16* const Bb[3] = {SMEM + 12288, SMEM + 20480, SMEM + 28672}; // 256x32

  const int cpx = gridDim.x >> 3;          // bijective XCD swizzle (3072%8==0)
  const int swz = (blockIdx.x & 7) * cpx + (blockIdx.x >> 3);
  const int bm = swz / 6;
  const int bn = swz - bm * 6;
  const int tid = threadIdx.x;
  const int lane = tid & 63;
  const int w = tid >> 6;
  const int wm = w >> 2, wn = w & 3;
  const int laneM = lane & 15, laneHi = lane >> 4;
  const long mRow0 = (long)bm * 128;
  const int  nRow0 = bn * 256;

  const int aR = tid >> 2;
  const int aCol = ((tid & 3) ^ (aR & 3)) * 8;
  const u16* const aS = A + (mRow0 + aR) * DD + aCol;
  const int bR = tid >> 2;
  const int bCol = ((tid & 3) ^ (bR & 3)) * 8;
  const u16* const bS = W + (long)(nRow0 + bR) * DD + bCol;

#define STAGE(kt, abu, bbu)                                                 \
  gload_lds16(aS + (kt) * 32,            (abu) + w * 512);                  \
  gload_lds16(bS + (kt) * 32,            (bbu) + (w * 64) * 8);             \
  gload_lds16(bS + (kt) * 32 + 128 * DD, (bbu) + (512 + w * 64) * 8);

  f32x4 acc[4][4] = {};
  const int abSwz = laneHi ^ (laneM & 3);

  STAGE(0, Ab[0], Bb[0]);
  STAGE(1, Ab[1], Bb[1]);
  asm volatile("s_waitcnt vmcnt(3)" ::: "memory");
  __builtin_amdgcn_sched_barrier(0);
  BAR();

#pragma unroll
  for (int kt = 0; kt < 16; ++kt) {
    const u16* const Abu = Ab[kt % 3];
    const u16* const Bbu = Bb[kt % 3];

    if (kt < 14) {
      STAGE(kt + 2, Ab[(kt + 2) % 3], Bb[(kt + 2) % 3]);
      asm volatile("s_waitcnt vmcnt(6)" ::: "memory");
    } else if (kt == 14) {
      asm volatile("s_waitcnt vmcnt(3)" ::: "memory");
    } else {
      asm volatile("s_waitcnt vmcnt(0)" ::: "memory");
    }
    __builtin_amdgcn_sched_barrier(0);
    BAR();

    bf16x8 a[4], b[4];
#pragma unroll
    for (int q = 0; q < 4; ++q) {
      const int ra = wm * 64 + q * 16 + laneM;
      a[q] = *reinterpret_cast<const bf16x8*>(&Abu[ra * 32 + abSwz * 8]);
      const int rb = wn * 64 + q * 16 + laneM;
      b[q] = *reinterpret_cast<const bf16x8*>(&Bbu[rb * 32 + abSwz * 8]);
    }

    __builtin_amdgcn_s_setprio(1);
#pragma unroll
    for (int q = 0; q < 4; ++q)
#pragma unroll
      for (int r = 0; r < 4; ++r)
        acc[q][r] = __builtin_amdgcn_mfma_f32_16x16x32_bf16(
            a[q], b[r], acc[q][r], 0, 0, 0);
    __builtin_amdgcn_s_setprio(0);
    BAR();
  }
#undef STAGE

  float bvv[4];
#pragma unroll
  for (int ni = 0; ni < 4; ++ni)
    bvv[ni] = bias[nRow0 + wn * 64 + ni * 16 + laneM];
  u16* const ep = SMEM;
#pragma unroll
  for (int mi = 0; mi < 4; ++mi)
#pragma unroll
    for (int ni = 0; ni < 4; ++ni)
#pragma unroll
      for (int r = 0; r < 4; ++r)
        ep[(wm * 64 + mi * 16 + laneHi * 4 + r) * 280 +
           wn * 64 + ni * 16 + laneM] = f2bf(acc[mi][ni][r] + bvv[ni]);
  asm volatile("s_waitcnt lgkmcnt(0)" ::: "memory");
  __builtin_amdgcn_sched_barrier(0);
  BAR();
#pragma unroll
  for (int it = 0; it < 8; ++it) {
    const int row = tid >> 2;
    const int col = ((tid & 3) + it * 4) * 8;
    uint4 v = *reinterpret_cast<const uint4*>(&ep[row * 280 + col]);
    *reinterpret_cast<uint4*>(
        &out[(mRow0 + row) * (long)NG + nRow0 + col]) = v;
  }
}

// ---------------------------------------------------------------------------
// Single-pass fused scan (decoupled lookback, ticket-ordered => deadlock-free
// regardless of dispatch order: a block's lookback only waits on lower
// tickets, all of which were claimed by already-running blocks that publish
// their AGG without waiting).
// Block = (chunk k, chain-group g): 512 threads x 2 chains = 1024 chains,
// 8 groups x 128 chunks = 1024 blocks. Z,F read once; (f, u=(1-f)z) kept
// packed bf16 in registers; replay reads only O.
// flags[k*8+g]: 0=none, 1=AGG (Abuf/Bbuf valid), 2=INC (Cend valid).
// MODE 0: write bf16 xb. MODE 1: write fp32 xout.
// ---------------------------------------------------------------------------
template <int MODE>
__global__ __launch_bounds__(512) void scan_fused(
    const u16* __restrict__ gates, const float* __restrict__ h0,
    const int layer, float* __restrict__ Abuf, float* __restrict__ Bbuf,
    float* __restrict__ Cend, int* flags, int* ticket,
    float* __restrict__ xout, u16* __restrict__ xb,
    float* __restrict__ hout)
{
  __shared__ int s_tkt;
  if (threadIdx.x == 0) s_tkt = atomicAdd(ticket, 1);
  __syncthreads();
  const int tkt = s_tkt;
  const int k = tkt >> 3;          // chunk 0..127 (chunk-major tickets)
  const int g = tkt & 7;           // chain-group
  const int tid = threadIdx.x;
  const int chain = g * 1024 + tid * 2;
  const int b = chain >> 9;
  const int h = chain & 511;
  const u16* gz = gates + ((size_t)b * TT + (size_t)k * CS) * NG + h;

  // ---- local pass: read Z,F; fp32 (A,B); keep (u,f) packed bf16 in regs
  float A0 = 1.f, B0 = 0.f, A1 = 1.f, B1 = 0.f;
  unsigned fu0[CS], fu1[CS];
#pragma unroll
  for (int t = 0; t < CS; ++t) {
    u16x2 zv = *reinterpret_cast<const u16x2*>(gz + (size_t)t * NG);
    u16x2 fv = *reinterpret_cast<const u16x2*>(gz + (size_t)t * NG + 512);
    float z0 = bf2f(zv[0]); z0 = z0 > 0.f ? z0 : 0.f;
    float z1 = bf2f(zv[1]); z1 = z1 > 0.f ? z1 : 0.f;
    const float f0 = sigm(bf2f(fv[0]));
    const float f1 = sigm(bf2f(fv[1]));
    const float u0 = (1.f - f0) * z0;
    const float u1 = (1.f - f1) * z1;
    fu0[t] = (unsigned)f2bf(u0) | ((unsigned)f2bf(f0) << 16);
    fu1[t] = (unsigned)f2bf(u1) | ((unsigned)f2bf(f1) << 16);
    A0 *= f0; B0 = f0 * B0 + u0;
    A1 *= f1; B1 = f1 * B1 + u1;
  }

  // publish aggregate (A,B)
  *reinterpret_cast<float2*>(&Abuf[(size_t)k * NCHAIN + chain]) =
      make_float2(A0, A1);
  *reinterpret_cast<float2*>(&Bbuf[(size_t)k * NCHAIN + chain]) =
      make_float2(B0, B1);
  __syncthreads();
  if (tid == 0) {
    __threadfence();
    __hip_atomic_store(&flags[k * 8 + g], 1, __ATOMIC_RELEASE,
                       __HIP_MEMORY_SCOPE_AGENT);
  }

  // ---- lookback: compose AGGs backwards until an INC (or j<0 -> h0)
  float cs0, cs1;
  {
    float Ac0 = 1.f, Bc0 = 0.f, Ac1 = 1.f, Bc1 = 0.f;
    float base0, base1;
    bool done = false;
    for (int j = k - 1; j >= 0; --j) {
      int fl;
      do {
        fl = __hip_atomic_load(&flags[j * 8 + g], __ATOMIC_ACQUIRE,
                               __HIP_MEMORY_SCOPE_AGENT);
        if (!fl) __builtin_amdgcn_s_sleep(1);
      } while (!fl);
      if (fl == 2) {
        float2 ce = *reinterpret_cast<const float2*>(
            &Cend[(size_t)j * NCHAIN + chain]);
        base0 = ce.x; base1 = ce.y;
        done = true;
        break;
      }
      float2 aj = *reinterpret_cast<const float2*>(
          &Abuf[(size_t)j * NCHAIN + chain]);
      float2 bj = *reinterpret_cast<const float2*>(
          &Bbuf[(size_t)j * NCHAIN + chain]);
      Bc0 = Ac0 * bj.x + Bc0; Ac0 *= aj.x;
      Bc1 = Ac1 * bj.y + Bc1; Ac1 *= aj.y;
    }
    if (!done) {
      base0 = h0[b * 1024 + layer * 512 + h];
      base1 = h0[b * 1024 + layer * 512 + h + 1];
    }
    cs0 = Ac0 * base0 + Bc0;
    cs1 = Ac1 * base1 + Bc1;
  }

  // publish inclusive chunk-end state
  const float ce0 = A0 * cs0 + B0;
  const float ce1 = A1 * cs1 + B1;
  *reinterpret_cast<float2*>(&Cend[(size_t)k * NCHAIN + chain]) =
      make_float2(ce0, ce1);
  __syncthreads();
  if (tid == 0) {
    __threadfence();
    __hip_atomic_store(&flags[k * 8 + g], 2, __ATOMIC_RELEASE,
                       __HIP_MEMORY_SCOPE_AGENT);
  }
  if (k == NCH - 1) {
    hout[b * 1024 + layer * 512 + h] = ce0;
    hout[b * 1024 + layer * 512 + h + 1] = ce1;
  }

  // ---- replay from registers; read only O
  float c0 = cs0, c1 = cs1;
  const size_t xrow0 = ((size_t)b * TT + (size_t)k * CS) * DD + h;
#pragma unroll
  for (int t = 0; t < CS; ++t) {
    u16x2 ov = *reinterpret_cast<const u16x2*>(gz + (size_t)t * NG + 1024);
    const float f0 = bf2f((u16)(fu0[t] >> 16));
    const float u0 = bf2f((u16)(fu0[t] & 0xffffu));
    const float f1 = bf2f((u16)(fu1[t] >> 16));
    const float u1 = bf2f((u16)(fu1[t] & 0xffffu));
    c0 = f0 * c0 + u0;
    c1 = f1 * c1 + u1;
    const float x0 = sigm(bf2f(ov[0])) * c0;
    const float x1 = sigm(bf2f(ov[1])) * c1;
    if (MODE == 0) {
      u16x2 pk; pk[0] = f2bf(x0); pk[1] = f2bf(x1);
      *reinterpret_cast<u16x2*>(xb + xrow0 + (size_t)t * DD) = pk;
    } else {
      *reinterpret_cast<float2*>(xout + xrow0 + (size_t)t * DD) =
          make_float2(x0, x1);
    }
  }
}

extern "C" void kernel_launch(void* const* d_in, const int* in_sizes, int n_in,
                              void* d_out, int out_size, void* d_ws, size_t ws_size,
                              hipStream_t stream) {
  const float* x  = (const float*)d_in[0];
  const float* h0 = (const float*)d_in[1];
  const float* W0 = (const float*)d_in[2];
  const float* b0 = (const float*)d_in[3];
  const float* W1 = (const float*)d_in[4];
  const float* b1 = (const float*)d_in[5];

  float* out_x = (float*)d_out;                       // [B*T, 512]
  float* out_h = out_x + (size_t)BB * TT * DD;        // [B, 2, 512]

  // workspace layout (~284 MB)
  char* ws = (char*)d_ws;
  u16* gates = (u16*)ws;                              // bf16 [B*T,1536] 201.3MB
  size_t off = (size_t)BB * TT * NG * 2;
  u16* xb  = (u16*)(ws + off);                        // bf16 [B*T,512]  67.1MB
  off += (size_t)BB * TT * DD * 2;
  u16* W0b = (u16*)(ws + off); off += (size_t)NG * DD * 2;
  u16* W1b = (u16*)(ws + off); off += (size_t)NG * DD * 2;
  float* Abuf = (float*)(ws + off); off += (size_t)NCH * NCHAIN * 4; // 4MB
  float* Bbuf = (float*)(ws + off); off += (size_t)NCH * NCHAIN * 4; // 4MB
  float* Cend = (float*)(ws + off); off += (size_t)NCH * NCHAIN * 4; // 4MB
  int* meta0 = (int*)(ws + off); off += 2048 * 4;     // [0]=ticket, [8..]=flags
  int* meta1 = (int*)(ws + off); off += 2048 * 4;

  dim3 blk(256);
  dim3 gemmGrid((NG / 256) * ((BB * TT) / 128));      // 3072
  dim3 gemmBlk(512);
  dim3 scanGrid(NCH * 8);                             // 1024 blocks
  dim3 scanBlk(512);

  // zero tickets+flags for both layers (one stream-ordered memset)
  hipMemsetAsync(meta0, 0, 2 * 2048 * 4, stream);

  f32_to_bf16<<<2048, blk, 0, stream>>>(x, xb, (long)BB * TT * DD);
  f32_to_bf16<<<384, blk, 0, stream>>>(W0, W0b, (long)NG * DD);
  f32_to_bf16<<<384, blk, 0, stream>>>(W1, W1b, (long)NG * DD);

  // Layer 0
  gemmB<<<gemmGrid, gemmBlk, 0, stream>>>(xb, W0b, b0, gates);
  scan_fused<0><<<scanGrid, scanBlk, 0, stream>>>(
      gates, h0, 0, Abuf, Bbuf, Cend, meta0 + 8, meta0,
      out_x, xb, out_h);
  // Layer 1 (xb rewritten by scan_fused<0> after gemm0 consumed it)
  gemmB<<<gemmGrid, gemmBlk, 0, stream>>>(xb, W1b, b1, gates);
  scan_fused<1><<<scanGrid, scanBlk, 0, stream>>>(
      gates, h0, 1, Abuf, Bbuf, Cend, meta1 + 8, meta1,
      out_x, nullptr, out_h);
}

// Round 11
// 473.240 us; speedup vs baseline: 3.0903x; 3.0903x over previous
//
#include <hip/hip_runtime.h>
#include <cstdint>
#include <cstddef>

// Problem constants: B=16, T=4096, D_IN=H=512, L=2, 3H=1536
#define BB 16
#define TT 4096
#define DD 512
#define NG 1536
#define NCH 128           // chunks per chain
#define CS  (TT / NCH)    // 32 timesteps per chunk
#define NCHAIN (BB * DD)  // 8192 chains

typedef __bf16 bf16x8 __attribute__((ext_vector_type(8)));
typedef float f32x4 __attribute__((ext_vector_type(4)));
typedef unsigned short u16;
typedef __attribute__((ext_vector_type(4))) unsigned short u16x4;
typedef __attribute__((ext_vector_type(8))) unsigned short u16x8;

__device__ __forceinline__ u16 f2bf(float f) {
  union { float f; unsigned u; } v; v.f = f;
  return (u16)((v.u + 0x7FFFu + ((v.u >> 16) & 1u)) >> 16);
}
__device__ __forceinline__ float bf2f(u16 s) {
  union { unsigned u; float f; } v; v.u = ((unsigned)s) << 16;
  return v.f;
}
__device__ __forceinline__ float sigm(float x) {
  return 1.f / (1.f + __expf(-x));
}

// async global->LDS, 16B per lane. LDS dest = wave-uniform base + lane*16.
__device__ __forceinline__ void gload_lds16(const void* g, void* l) {
  __builtin_amdgcn_global_load_lds(
      (const __attribute__((address_space(1))) unsigned*)g,
      (__attribute__((address_space(3))) unsigned*)l, 16, 0, 0);
}

#define BAR() __builtin_amdgcn_s_barrier()

// ---------------------------------------------------------------------------
// fp32 -> bf16 bulk convert (x: 201 MB traffic; W0/W1: tiny)
// ---------------------------------------------------------------------------
__global__ __launch_bounds__(256) void f32_to_bf16(
    const float* __restrict__ in, u16* __restrict__ out, long n)
{
  const long stride = (long)gridDim.x * 256 * 8;
  for (long i = ((long)blockIdx.x * 256 + threadIdx.x) * 8; i < n; i += stride) {
    float4 a = *reinterpret_cast<const float4*>(in + i);
    float4 b = *reinterpret_cast<const float4*>(in + i + 4);
    uint4 p;
    p.x = (unsigned)f2bf(a.x) | ((unsigned)f2bf(a.y) << 16);
    p.y = (unsigned)f2bf(a.z) | ((unsigned)f2bf(a.w) << 16);
    p.z = (unsigned)f2bf(b.x) | ((unsigned)f2bf(b.y) << 16);
    p.w = (unsigned)f2bf(b.z) | ((unsigned)f2bf(b.w) << 16);
    *reinterpret_cast<uint4*>(out + i) = p;
  }
}

// ---------------------------------------------------------------------------
// Fused GEMM + gate transform + chunk aggregates.
// Tile: 128 rows (M) x 192 cols = {Z,F,O} x 64 h-columns (hc..hc+63).
// K-loop: R9-validated triple-buffer depth-2, counted vmcnt(6); staging is
// wave-uniform 3 gloads/wave (waves w and w+4 duplicate the same B-quarter:
// same src, same dest, same data -> benign).
// Epilogue: bounce raw bf16 gates to LDS -> transform Z,F slots in place to
// u=(1-ff)*relu(z), ff=sigm(f) (O stays raw) -> coalesced copy-out of all 3
// planes -> 256-thread in-LDS scan produces per-chunk (A,B) aggregates.
// Eliminates scan_phase1 entirely.
// ---------------------------------------------------------------------------
__global__ __launch_bounds__(512, 4) void gemmF(
    const u16* __restrict__ A, const u16* __restrict__ W,
    const float* __restrict__ bias, u16* __restrict__ out,
    float* __restrict__ Abuf, float* __restrict__ Bbuf)
{
  __shared__ __align__(16) u16 SMEM[30720];   // 60 KB; epilogue reuses 50 KB
  u16* const AbB = SMEM;            // 3 bufs x 128x32
  u16* const BbB = SMEM + 12288;    // 3 bufs x 192x32

  // bijective XCD swizzle (nwg = 4096 % 8 == 0); slice fastest -> blocks on
  // one XCD share the A-panel.
  const int cpx = gridDim.x >> 3;
  const int swz = (blockIdx.x & 7) * cpx + (blockIdx.x >> 3);
  const int bm = swz >> 3;              // 0..511 (M tiles of 128)
  const int hc = (swz & 7) * 64;        // h-slice base
  const int tid = threadIdx.x;
  const int lane = tid & 63;
  const int w = tid >> 6;
  const int wm = w >> 2, wn = w & 3;
  const int laneM = lane & 15, laneHi = lane >> 4;
  const long mRow0 = (long)bm * 128;

  // staging sources (per-lane). LDS B rows: [0,64)=Z, [64,128)=F, [128,192)=O
  // mapping LDS row r -> W row (r>>6)*512 + hc + (r&63).
  const int lr = lane >> 2;             // 0..15
  const int lc = (lane & 3) * 8;        // u16 col within 64B row-chunk
  const u16* const aS  = A + (mRow0 + w * 16 + lr) * DD + lc;
  const u16* const bS1 = W + ((long)(w >> 2) * 512 + hc + (w & 3) * 16 + lr) * DD + lc;
  const u16* const bS2 = W + ((long)1024 + hc + (w & 3) * 16 + lr) * DD + lc;

#define STAGE(kt, i)                                                        \
  gload_lds16(aS  + (kt) * 32, AbB + (i) * 4096 + w * 512);                 \
  gload_lds16(bS1 + (kt) * 32, BbB + (i) * 6144 + w * 512);                 \
  gload_lds16(bS2 + (kt) * 32, BbB + (i) * 6144 + (8 + (w & 3)) * 512);

  f32x4 acc[4][3] = {};

  STAGE(0, 0);
  STAGE(1, 1);
  asm volatile("s_waitcnt vmcnt(3)" ::: "memory");   // S0 landed
  __builtin_amdgcn_sched_barrier(0);
  BAR();

#pragma unroll
  for (int kt = 0; kt < 16; ++kt) {
    const u16* const Abu = AbB + (kt % 3) * 4096;
    const u16* const Bbu = BbB + (kt % 3) * 6144;

    if (kt < 14) {
      STAGE(kt + 2, (kt + 2) % 3);
      asm volatile("s_waitcnt vmcnt(6)" ::: "memory");  // S(kt) retired
    } else if (kt == 14) {
      asm volatile("s_waitcnt vmcnt(3)" ::: "memory");
    } else {
      asm volatile("s_waitcnt vmcnt(0)" ::: "memory");
    }
    __builtin_amdgcn_sched_barrier(0);
    BAR();

    bf16x8 a[4], b[3];
#pragma unroll
    for (int q = 0; q < 4; ++q)
      a[q] = *reinterpret_cast<const bf16x8*>(
          &Abu[(wm * 64 + q * 16 + laneM) * 32 + laneHi * 8]);
#pragma unroll
    for (int r = 0; r < 3; ++r)
      b[r] = *reinterpret_cast<const bf16x8*>(
          &Bbu[(wn * 48 + r * 16 + laneM) * 32 + laneHi * 8]);

    __builtin_amdgcn_s_setprio(1);
#pragma unroll
    for (int q = 0; q < 4; ++q)
#pragma unroll
      for (int r = 0; r < 3; ++r)
        acc[q][r] = __builtin_amdgcn_mfma_f32_16x16x32_bf16(
            a[q], b[r], acc[q][r], 0, 0, 0);
    __builtin_amdgcn_s_setprio(0);
    BAR();
  }
#undef STAGE

  // ---- epilogue 1: bounce raw bf16 gates (+bias) to LDS [128][200]
  float bvv[3];
#pragma unroll
  for (int ni = 0; ni < 3; ++ni) {
    const int col = wn * 48 + ni * 16 + laneM;           // 0..191
    bvv[ni] = bias[(col >> 6) * 512 + hc + (col & 63)];
  }
  u16* const ep = SMEM;
#define EPS 200
#pragma unroll
  for (int mi = 0; mi < 4; ++mi)
#pragma unroll
    for (int ni = 0; ni < 3; ++ni)
#pragma unroll
      for (int r = 0; r < 4; ++r)
        ep[(wm * 64 + mi * 16 + laneHi * 4 + r) * EPS +
           wn * 48 + ni * 16 + laneM] = f2bf(acc[mi][ni][r] + bvv[ni]);
  asm volatile("s_waitcnt lgkmcnt(0)" ::: "memory");
  __builtin_amdgcn_sched_barrier(0);
  BAR();

  // ---- epilogue 2: transform Z,F slots in place (u, ff); O untouched.
#pragma unroll
  for (int it = 0; it < 2; ++it) {
    const int idx = it * 512 + tid;       // 0..1023
    const int row = idx >> 3;
    const int jg = idx & 7;
    u16* const pz = &ep[row * EPS + jg * 8];
    u16* const pf = pz + 64;
    u16x8 z8 = *reinterpret_cast<u16x8*>(pz);
    u16x8 f8 = *reinterpret_cast<u16x8*>(pf);
    u16x8 u8, ff8;
#pragma unroll
    for (int i = 0; i < 8; ++i) {
      float z = bf2f(z8[i]); z = z > 0.f ? z : 0.f;
      const float ff = sigm(bf2f(f8[i]));
      u8[i] = f2bf((1.f - ff) * z);
      ff8[i] = f2bf(ff);
    }
    *reinterpret_cast<u16x8*>(pz) = u8;
    *reinterpret_cast<u16x8*>(pf) = ff8;
  }
  asm volatile("s_waitcnt lgkmcnt(0)" ::: "memory");
  __builtin_amdgcn_sched_barrier(0);
  BAR();

  // ---- epilogue 3: coalesced copy-out of the 3 planes (reads only)
  {
    const int row = tid >> 2;             // 0..127
#pragma unroll
    for (int it = 0; it < 6; ++it) {
      const int g = (tid & 3) + it * 4;   // 0..23 granules of 8 u16
      uint4 v = *reinterpret_cast<const uint4*>(&ep[row * EPS + g * 8]);
      const int plane = g >> 3;
      const int j8 = (g & 7) * 8;
      *reinterpret_cast<uint4*>(
          &out[(mRow0 + row) * (long)NG + plane * 512 + hc + j8]) = v;
    }
  }

  // ---- epilogue 4: per-chunk (A,B) aggregates from LDS (reads only)
  if (tid < 256) {
    const int chunk = tid >> 6;           // 0..3
    const int j = tid & 63;
    float Aa = 1.f, Bb_ = 0.f;
#pragma unroll
    for (int t = 0; t < CS; ++t) {
      const int row = chunk * CS + t;
      const float ff = bf2f(ep[row * EPS + 64 + j]);
      const float u  = bf2f(ep[row * EPS + j]);
      Bb_ = ff * Bb_ + u;
      Aa *= ff;
    }
    const int kg = (bm & 31) * 4 + chunk;       // global chunk 0..127
    const int b = bm >> 5;
    Abuf[(size_t)kg * NCHAIN + b * 512 + hc + j] = Aa;
    Bbuf[(size_t)kg * NCHAIN + b * 512 + hc + j] = Bb_;
  }
#undef EPS
}

// ---------------------------------------------------------------------------
// Phase 2: per chain, sequential scan over NCH chunk transfers. (validated)
// ---------------------------------------------------------------------------
__global__ __launch_bounds__(256) void scan_phase2(
    const float* __restrict__ Ain, const float* __restrict__ Bin,
    const float* __restrict__ h0, const int layer,
    float* __restrict__ cstart, float* __restrict__ hout)
{
  const int chain = blockIdx.x * 256 + threadIdx.x;  // 0..8191
  const int b = chain >> 9;
  const int h = chain & 511;

  float c = h0[b * 1024 + layer * 512 + h];
#pragma unroll 8
  for (int k = 0; k < NCH; ++k) {
    cstart[(size_t)k * NCHAIN + chain] = c;
    c = Ain[(size_t)k * NCHAIN + chain] * c + Bin[(size_t)k * NCHAIN + chain];
  }
  hout[b * 1024 + layer * 512 + h] = c;
}

// ---------------------------------------------------------------------------
// Phase 3: replay chunks from cstart. gates planes now hold (u, ff, o_raw):
// c = ff*c + u; x = sigm(o)*c. Only ONE transcendental per element.
// MODE 0: write bf16 xb. MODE 1: write fp32 x.
// ---------------------------------------------------------------------------
template <int MODE>
__global__ __launch_bounds__(256) void scan_phase3(
    const u16* __restrict__ gates, const float* __restrict__ cstart,
    float* __restrict__ xout, u16* __restrict__ xb)
{
  const int tid = blockIdx.x * 256 + threadIdx.x;
  const int cg = tid & 2047;
  const int k  = tid >> 11;
  const int b  = cg >> 7;
  const int h4 = cg & 127;
  const int chain = b * 512 + h4 * 4;

  const u16* g = gates + ((size_t)b * TT + (size_t)k * CS) * NG + h4 * 4;
  const size_t xrow0 = ((size_t)b * TT + (size_t)k * CS) * DD + h4 * 4;

  float c[4];
#pragma unroll
  for (int j = 0; j < 4; ++j) c[j] = cstart[(size_t)k * NCHAIN + chain + j];

  for (int t = 0; t < CS; t += 4) {
    u16x4 uv[4], fv[4], ov[4];
#pragma unroll
    for (int u = 0; u < 4; ++u) {
      const u16* gt = g + (size_t)(t + u) * NG;
      uv[u] = *reinterpret_cast<const u16x4*>(gt);
      fv[u] = *reinterpret_cast<const u16x4*>(gt + 512);
      ov[u] = *reinterpret_cast<const u16x4*>(gt + 1024);
    }
#pragma unroll
    for (int u = 0; u < 4; ++u) {
      float xv[4];
#pragma unroll
      for (int j = 0; j < 4; ++j) {
        const float ff = bf2f(fv[u][j]);
        const float uu = bf2f(uv[u][j]);
        c[j] = ff * c[j] + uu;
        xv[j] = sigm(bf2f(ov[u][j])) * c[j];
      }
      if (MODE == 0) {
        u16x4 pk;
#pragma unroll
        for (int j = 0; j < 4; ++j) pk[j] = f2bf(xv[j]);
        *reinterpret_cast<u16x4*>(xb + xrow0 + (size_t)(t + u) * DD) = pk;
      } else {
        *reinterpret_cast<float4*>(xout + xrow0 + (size_t)(t + u) * DD) =
            make_float4(xv[0], xv[1], xv[2], xv[3]);
      }
    }
  }
}

extern "C" void kernel_launch(void* const* d_in, const int* in_sizes, int n_in,
                              void* d_out, int out_size, void* d_ws, size_t ws_size,
                              hipStream_t stream) {
  const float* x  = (const float*)d_in[0];
  const float* h0 = (const float*)d_in[1];
  const float* W0 = (const float*)d_in[2];
  const float* b0 = (const float*)d_in[3];
  const float* W1 = (const float*)d_in[4];
  const float* b1 = (const float*)d_in[5];

  float* out_x = (float*)d_out;                       // [B*T, 512]
  float* out_h = out_x + (size_t)BB * TT * DD;        // [B, 2, 512]

  // workspace layout (~284 MB)
  char* ws = (char*)d_ws;
  u16* gates = (u16*)ws;                              // bf16 [B*T,1536] 201.3MB
  size_t off = (size_t)BB * TT * NG * 2;
  u16* xb  = (u16*)(ws + off);                        // bf16 [B*T,512]  67.1MB
  off += (size_t)BB * TT * DD * 2;
  u16* W0b = (u16*)(ws + off); off += (size_t)NG * DD * 2;
  u16* W1b = (u16*)(ws + off); off += (size_t)NG * DD * 2;
  float* Abuf   = (float*)(ws + off); off += (size_t)NCH * NCHAIN * 4; // 4MB
  float* Bbuf   = (float*)(ws + off); off += (size_t)NCH * NCHAIN * 4; // 4MB
  float* cstart = (float*)(ws + off);                                   // 4MB

  dim3 blk(256);
  dim3 gemmGrid(((BB * TT) / 128) * 8);               // 512 M-tiles x 8 slices
  dim3 gemmBlk(512);
  dim3 pGrid((NCHAIN / 4 * NCH) / 256);               // 1024 blocks
  dim3 p2Grid(NCHAIN / 256);                          // 32

  f32_to_bf16<<<2048, blk, 0, stream>>>(x, xb, (long)BB * TT * DD);
  f32_to_bf16<<<384, blk, 0, stream>>>(W0, W0b, (long)NG * DD);
  f32_to_bf16<<<384, blk, 0, stream>>>(W1, W1b, (long)NG * DD);

  // Layer 0
  gemmF<<<gemmGrid, gemmBlk, 0, stream>>>(xb, W0b, b0, gates, Abuf, Bbuf);
  scan_phase2<<<p2Grid, blk, 0, stream>>>(Abuf, Bbuf, h0, 0, cstart, out_h);
  scan_phase3<0><<<pGrid, blk, 0, stream>>>(gates, cstart, out_x, xb);
  // Layer 1 (xb rewritten by phase3 only after gemm0 consumed it)
  gemmF<<<gemmGrid, gemmBlk, 0, stream>>>(xb, W1b, b1, gates, Abuf, Bbuf);
  scan_phase2<<<p2Grid, blk, 0, stream>>>(Abuf, Bbuf, h0, 1, cstart, out_h);
  scan_phase3<1><<<pGrid, blk, 0, stream>>>(gates, cstart, out_x, nullptr);
}

// Round 12
// 465.581 us; speedup vs baseline: 3.1411x; 1.0165x over previous
//
#include <hip/hip_runtime.h>
#include <cstdint>
#include <cstddef>

// Problem constants: B=16, T=4096, D_IN=H=512, L=2, 3H=1536
#define BB 16
#define TT 4096
#define DD 512
#define NG 1536
#define NCH 128           // chunks per chain
#define CS  (TT / NCH)    // 32 timesteps per chunk
#define NCHAIN (BB * DD)  // 8192 chains

typedef __bf16 bf16x8 __attribute__((ext_vector_type(8)));
typedef float f32x4 __attribute__((ext_vector_type(4)));
typedef unsigned short u16;
typedef __attribute__((ext_vector_type(4))) unsigned short u16x4;

__device__ __forceinline__ u16 f2bf(float f) {
  union { float f; unsigned u; } v; v.f = f;
  return (u16)((v.u + 0x7FFFu + ((v.u >> 16) & 1u)) >> 16);
}
__device__ __forceinline__ float bf2f(u16 s) {
  union { unsigned u; float f; } v; v.u = ((unsigned)s) << 16;
  return v.f;
}
__device__ __forceinline__ float sigm(float x) {
  return 1.f / (1.f + __expf(-x));
}

// async global->LDS, 16B per lane. LDS dest = wave-uniform base + lane*16.
__device__ __forceinline__ void gload_lds16(const void* g, void* l) {
  __builtin_amdgcn_global_load_lds(
      (const __attribute__((address_space(1))) unsigned*)g,
      (__attribute__((address_space(3))) unsigned*)l, 16, 0, 0);
}

#define BAR() __builtin_amdgcn_s_barrier()

// ---------------------------------------------------------------------------
// fp32 -> bf16 bulk convert (x: 201 MB traffic; W0/W1: tiny)
// ---------------------------------------------------------------------------
__global__ __launch_bounds__(256) void f32_to_bf16(
    const float* __restrict__ in, u16* __restrict__ out, long n)
{
  const long stride = (long)gridDim.x * 256 * 8;
  for (long i = ((long)blockIdx.x * 256 + threadIdx.x) * 8; i < n; i += stride) {
    float4 a = *reinterpret_cast<const float4*>(in + i);
    float4 b = *reinterpret_cast<const float4*>(in + i + 4);
    uint4 p;
    p.x = (unsigned)f2bf(a.x) | ((unsigned)f2bf(a.y) << 16);
    p.y = (unsigned)f2bf(a.z) | ((unsigned)f2bf(a.w) << 16);
    p.z = (unsigned)f2bf(b.x) | ((unsigned)f2bf(b.y) << 16);
    p.w = (unsigned)f2bf(b.z) | ((unsigned)f2bf(b.w) << 16);
    *reinterpret_cast<uint4*>(out + i) = p;
  }
}

// ---------------------------------------------------------------------------
// GEMM (R9 structure, validated; ONLY change: correct bank swizzle).
// 128x256 tile, BK=32, 8 waves of 64x64, triple-buffered depth-2 prefetch,
// counted vmcnt(6), LDS-bounce epilogue.
// Bank fix: 64B rows span only 16 banks (bank-set = (row&1, granule)).
// Old swizzle g^=(row&3) left a 4-way conflict (lanes 0,4,8,12 same group,
// SQ_LDS_BANK_CONFLICT = 1.4e7). Correct involution: g ^= (row>>1)&3 ->
// per 16-lane group all (row&1, g) combos hit exactly 2-way (free, m136).
// Read side: ((row>>1)&3) == ((laneM>>1)&3) for rows wm*64+q*16+laneM.
// ---------------------------------------------------------------------------
__global__ __launch_bounds__(512, 4) void gemmB(
    const u16* __restrict__ A, const u16* __restrict__ W,
    const float* __restrict__ bias, u16* __restrict__ out)
{
  __shared__ __align__(16) u16 SMEM[36864];   // 72 KB
  u16* const Ab[3] = {SMEM, SMEM + 4096, SMEM + 8192};           // 128x32
  u16* const Bb[3] = {SMEM + 12288, SMEM + 20480, SMEM + 28672}; // 256x32

  const int cpx = gridDim.x >> 3;          // bijective XCD swizzle (3072%8==0)
  const int swz = (blockIdx.x & 7) * cpx + (blockIdx.x >> 3);
  const int bm = swz / 6;
  const int bn = swz - bm * 6;
  const int tid = threadIdx.x;
  const int lane = tid & 63;
  const int w = tid >> 6;
  const int wm = w >> 2, wn = w & 3;
  const int laneM = lane & 15, laneHi = lane >> 4;
  const long mRow0 = (long)bm * 128;
  const int  nRow0 = bn * 256;

  // staging: LDS granule idx = tid -> row = tid>>2, phys granule = tid&3.
  // source logical granule = (tid&3) ^ ((row>>1)&3) = (tid&3) ^ ((tid>>3)&3).
  const int aR = tid >> 2;
  const int sCol = ((tid & 3) ^ ((tid >> 3) & 3)) * 8;   // pre-swizzled source
  const u16* const aS = A + (mRow0 + aR) * DD + sCol;
  // B second half: rows +128 -> ((row+128)>>1)&3 == ((row>>1)&3) (128/2=64≡0 mod 4)
  const u16* const bS = W + (long)(nRow0 + aR) * DD + sCol;

#define STAGE(kt, abu, bbu)                                                 \
  gload_lds16(aS + (kt) * 32,            (abu) + w * 512);                  \
  gload_lds16(bS + (kt) * 32,            (bbu) + (w * 64) * 8);             \
  gload_lds16(bS + (kt) * 32 + 128 * DD, (bbu) + (512 + w * 64) * 8);

  f32x4 acc[4][4] = {};
  const int abSwz = laneHi ^ ((laneM >> 1) & 3);   // == laneHi ^ ((row>>1)&3)

  STAGE(0, Ab[0], Bb[0]);
  STAGE(1, Ab[1], Bb[1]);
  asm volatile("s_waitcnt vmcnt(3)" ::: "memory");   // S0 landed
  __builtin_amdgcn_sched_barrier(0);
  BAR();

#pragma unroll
  for (int kt = 0; kt < 16; ++kt) {
    const u16* const Abu = Ab[kt % 3];
    const u16* const Bbu = Bb[kt % 3];

    if (kt < 14) {
      STAGE(kt + 2, Ab[(kt + 2) % 3], Bb[(kt + 2) % 3]);
      asm volatile("s_waitcnt vmcnt(6)" ::: "memory");  // S(kt) retired
    } else if (kt == 14) {
      asm volatile("s_waitcnt vmcnt(3)" ::: "memory");  // S14 retired
    } else {
      asm volatile("s_waitcnt vmcnt(0)" ::: "memory");  // S15 retired
    }
    __builtin_amdgcn_sched_barrier(0);
    BAR();

    bf16x8 a[4], b[4];
#pragma unroll
    for (int q = 0; q < 4; ++q) {
      const int ra = wm * 64 + q * 16 + laneM;
      a[q] = *reinterpret_cast<const bf16x8*>(&Abu[ra * 32 + abSwz * 8]);
      const int rb = wn * 64 + q * 16 + laneM;
      b[q] = *reinterpret_cast<const bf16x8*>(&Bbu[rb * 32 + abSwz * 8]);
    }

    __builtin_amdgcn_s_setprio(1);
#pragma unroll
    for (int q = 0; q < 4; ++q)
#pragma unroll
      for (int r = 0; r < 4; ++r)
        acc[q][r] = __builtin_amdgcn_mfma_f32_16x16x32_bf16(
            a[q], b[r], acc[q][r], 0, 0, 0);
    __builtin_amdgcn_s_setprio(0);
    BAR();
  }
#undef STAGE

  // ---- epilogue: LDS bounce (EPS=280), coalesced 16B/lane stores
  // (validated R5/R7/R9: WRITE_SIZE == 196.6 MB ideal).
  float bvv[4];
#pragma unroll
  for (int ni = 0; ni < 4; ++ni)
    bvv[ni] = bias[nRow0 + wn * 64 + ni * 16 + laneM];
  u16* const ep = SMEM;
#pragma unroll
  for (int mi = 0; mi < 4; ++mi)
#pragma unroll
    for (int ni = 0; ni < 4; ++ni)
#pragma unroll
      for (int r = 0; r < 4; ++r)
        ep[(wm * 64 + mi * 16 + laneHi * 4 + r) * 280 +
           wn * 64 + ni * 16 + laneM] = f2bf(acc[mi][ni][r] + bvv[ni]);
  asm volatile("s_waitcnt lgkmcnt(0)" ::: "memory");
  __builtin_amdgcn_sched_barrier(0);
  BAR();
#pragma unroll
  for (int it = 0; it < 8; ++it) {
    const int row = tid >> 2;
    const int col = ((tid & 3) + it * 4) * 8;
    uint4 v = *reinterpret_cast<const uint4*>(&ep[row * 280 + col]);
    *reinterpret_cast<uint4*>(
        &out[(mRow0 + row) * (long)NG + nRow0 + col]) = v;
  }
}

// ---------------------------------------------------------------------------
// Chunked parallel scan (R9-validated): 4 h-chains/thread, NCH=128.
// ---------------------------------------------------------------------------
__global__ __launch_bounds__(256) void scan_phase1(
    const u16* __restrict__ gates,
    float* __restrict__ Aout, float* __restrict__ Bout)
{
  const int tid = blockIdx.x * 256 + threadIdx.x;   // 0..262143
  const int cg = tid & 2047;
  const int k  = tid >> 11;
  const int b  = cg >> 7;
  const int h4 = cg & 127;
  const int chain = b * 512 + h4 * 4;

  const u16* g = gates + ((size_t)b * TT + (size_t)k * CS) * NG + h4 * 4;

  float Ac[4], Bc[4];
#pragma unroll
  for (int j = 0; j < 4; ++j) { Ac[j] = 1.f; Bc[j] = 0.f; }

  for (int t = 0; t < CS; t += 4) {
    u16x4 zv[4], fv[4];
#pragma unroll
    for (int u = 0; u < 4; ++u) {
      const u16* gt = g + (size_t)(t + u) * NG;
      zv[u] = *reinterpret_cast<const u16x4*>(gt);
      fv[u] = *reinterpret_cast<const u16x4*>(gt + 512);
    }
#pragma unroll
    for (int u = 0; u < 4; ++u)
#pragma unroll
      for (int j = 0; j < 4; ++j) {
        float z = bf2f(zv[u][j]); z = z > 0.f ? z : 0.f;
        const float f = sigm(bf2f(fv[u][j]));
        Ac[j] = f * Ac[j];
        Bc[j] = f * Bc[j] + (1.f - f) * z;
      }
  }
#pragma unroll
  for (int j = 0; j < 4; ++j) {
    Aout[(size_t)k * NCHAIN + chain + j] = Ac[j];
    Bout[(size_t)k * NCHAIN + chain + j] = Bc[j];
  }
}

__global__ __launch_bounds__(256) void scan_phase2(
    const float* __restrict__ Ain, const float* __restrict__ Bin,
    const float* __restrict__ h0, const int layer,
    float* __restrict__ cstart, float* __restrict__ hout)
{
  const int chain = blockIdx.x * 256 + threadIdx.x;  // 0..8191
  const int b = chain >> 9;
  const int h = chain & 511;

  float c = h0[b * 1024 + layer * 512 + h];
#pragma unroll 8
  for (int k = 0; k < NCH; ++k) {
    cstart[(size_t)k * NCHAIN + chain] = c;
    c = Ain[(size_t)k * NCHAIN + chain] * c + Bin[(size_t)k * NCHAIN + chain];
  }
  hout[b * 1024 + layer * 512 + h] = c;
}

// MODE 0: layer 0 -> write bf16 xb only. MODE 1: layer 1 -> write fp32 x.
template <int MODE>
__global__ __launch_bounds__(256) void scan_phase3(
    const u16* __restrict__ gates, const float* __restrict__ cstart,
    float* __restrict__ xout, u16* __restrict__ xb)
{
  const int tid = blockIdx.x * 256 + threadIdx.x;
  const int cg = tid & 2047;
  const int k  = tid >> 11;
  const int b  = cg >> 7;
  const int h4 = cg & 127;
  const int chain = b * 512 + h4 * 4;

  const u16* g = gates + ((size_t)b * TT + (size_t)k * CS) * NG + h4 * 4;
  const size_t xrow0 = ((size_t)b * TT + (size_t)k * CS) * DD + h4 * 4;

  float c[4];
#pragma unroll
  for (int j = 0; j < 4; ++j) c[j] = cstart[(size_t)k * NCHAIN + chain + j];

  for (int t = 0; t < CS; t += 4) {
    u16x4 zv[4], fv[4], ov[4];
#pragma unroll
    for (int u = 0; u < 4; ++u) {
      const u16* gt = g + (size_t)(t + u) * NG;
      zv[u] = *reinterpret_cast<const u16x4*>(gt);
      fv[u] = *reinterpret_cast<const u16x4*>(gt + 512);
      ov[u] = *reinterpret_cast<const u16x4*>(gt + 1024);
    }
#pragma unroll
    for (int u = 0; u < 4; ++u) {
      float xv[4];
#pragma unroll
      for (int j = 0; j < 4; ++j) {
        float z = bf2f(zv[u][j]); z = z > 0.f ? z : 0.f;
        const float f = sigm(bf2f(fv[u][j]));
        const float o = sigm(bf2f(ov[u][j]));
        c[j] = f * c[j] + (1.f - f) * z;
        xv[j] = o * c[j];
      }
      if (MODE == 0) {
        u16x4 pk;
#pragma unroll
        for (int j = 0; j < 4; ++j) pk[j] = f2bf(xv[j]);
        *reinterpret_cast<u16x4*>(xb + xrow0 + (size_t)(t + u) * DD) = pk;
      } else {
        *reinterpret_cast<float4*>(xout + xrow0 + (size_t)(t + u) * DD) =
            make_float4(xv[0], xv[1], xv[2], xv[3]);
      }
    }
  }
}

extern "C" void kernel_launch(void* const* d_in, const int* in_sizes, int n_in,
                              void* d_out, int out_size, void* d_ws, size_t ws_size,
                              hipStream_t stream) {
  const float* x  = (const float*)d_in[0];
  const float* h0 = (const float*)d_in[1];
  const float* W0 = (const float*)d_in[2];
  const float* b0 = (const float*)d_in[3];
  const float* W1 = (const float*)d_in[4];
  const float* b1 = (const float*)d_in[5];

  float* out_x = (float*)d_out;                       // [B*T, 512]
  float* out_h = out_x + (size_t)BB * TT * DD;        // [B, 2, 512]

  // workspace layout (~284 MB)
  char* ws = (char*)d_ws;
  u16* gates = (u16*)ws;                              // bf16 [B*T,1536] 201.3MB
  size_t off = (size_t)BB * TT * NG * 2;
  u16* xb  = (u16*)(ws + off);                        // bf16 [B*T,512]  67.1MB
  off += (size_t)BB * TT * DD * 2;
  u16* W0b = (u16*)(ws + off); off += (size_t)NG * DD * 2;
  u16* W1b = (u16*)(ws + off); off += (size_t)NG * DD * 2;
  float* Abuf   = (float*)(ws + off); off += (size_t)NCH * NCHAIN * 4; // 4MB
  float* Bbuf   = (float*)(ws + off); off += (size_t)NCH * NCHAIN * 4; // 4MB
  float* cstart = (float*)(ws + off);                                   // 4MB

  dim3 blk(256);
  dim3 gemmGrid((NG / 256) * ((BB * TT) / 128));      // 6*512 = 3072
  dim3 gemmBlk(512);
  dim3 pGrid((NCHAIN / 4 * NCH) / 256);               // 1024 blocks
  dim3 p2Grid(NCHAIN / 256);                          // 32

  f32_to_bf16<<<2048, blk, 0, stream>>>(x, xb, (long)BB * TT * DD);
  f32_to_bf16<<<384, blk, 0, stream>>>(W0, W0b, (long)NG * DD);
  f32_to_bf16<<<384, blk, 0, stream>>>(W1, W1b, (long)NG * DD);

  // Layer 0
  gemmB<<<gemmGrid, gemmBlk, 0, stream>>>(xb, W0b, b0, gates);
  scan_phase1<<<pGrid, blk, 0, stream>>>(gates, Abuf, Bbuf);
  scan_phase2<<<p2Grid, blk, 0, stream>>>(Abuf, Bbuf, h0, 0, cstart, out_h);
  scan_phase3<0><<<pGrid, blk, 0, stream>>>(gates, cstart, out_x, xb);
  // Layer 1 (xb rewritten by phase3 only after gemm0 consumed it)
  gemmB<<<gemmGrid, gemmBlk, 0, stream>>>(xb, W1b, b1, gates);
  scan_phase1<<<pGrid, blk, 0, stream>>>(gates, Abuf, Bbuf);
  scan_phase2<<<p2Grid, blk, 0, stream>>>(Abuf, Bbuf, h0, 1, cstart, out_h);
  scan_phase3<1><<<pGrid, blk, 0, stream>>>(gates, cstart, out_x, nullptr);
}